// Round 1
// baseline (557.232 us; speedup 1.0000x reference)
//
#include <hip/hip_runtime.h>
#include <hip/hip_bf16.h>
#include <math.h>

typedef unsigned short ushort_t;
typedef short short8 __attribute__((ext_vector_type(8)));
typedef float f32x4 __attribute__((ext_vector_type(4)));

#define N_TOK 512
#define EMBED 1024
#define INTER 4096
#define NCAT  5120   /* INTER + EMBED */
#define MROWS 24576  /* 48 * 512 */

__device__ __forceinline__ ushort_t f2bf(float f) {
  union { float f; unsigned int u; } c; c.f = f;
  unsigned int u = c.u;
  unsigned int r = u + 0x7fffu + ((u >> 16) & 1u);
  return (ushort_t)(r >> 16);
}

__device__ __forceinline__ void gld_lds16(const void* g, void* l) {
  __builtin_amdgcn_global_load_lds(
      (const __attribute__((address_space(1))) void*)g,
      (__attribute__((address_space(3))) void*)l, 16, 0, 0);
}

// ---- prep kernels -------------------------------------------------------

__global__ void prep_bcat(const float* __restrict__ bl, const float* __restrict__ br,
                          float* __restrict__ dst) {
  int i = blockIdx.x * 256 + threadIdx.x;
  if (i >= NCAT) return;
  dst[i] = (i < INTER) ? bl[i] : br[i - INTER];
}

__global__ void prep_wout(const float* __restrict__ W, ushort_t* __restrict__ dst) {
  int i = blockIdx.x * 256 + threadIdx.x;   // total EMBED*INTER, exact grid
  dst[i] = f2bf(W[i]);
}

// interp columns of [Wl;Wr] (96 -> P3), zero-pad to Kpad, bf16
__global__ void prep_wcat(const float* __restrict__ Wl, const float* __restrict__ Wr,
                          ushort_t* __restrict__ dst, int P3, int Kpad) {
  int i = blockIdx.x * 256 + threadIdx.x;
  int total = NCAT * Kpad;
  if (i >= total) return;
  int r = i / Kpad, j = i - r * Kpad;
  float v = 0.f;
  if (j < P3) {
    float scale = 96.0f / (float)P3;
    float src = (j + 0.5f) * scale - 0.5f;
    src = fminf(fmaxf(src, 0.0f), 95.0f);
    int i0 = (int)src;
    int i1 = min(i0 + 1, 95);
    float tt = src - (float)i0;
    const float* Wrow = (r < INTER) ? (Wl + (size_t)r * 96)
                                    : (Wr + (size_t)(r - INTER) * 96);
    v = Wrow[i0] * (1.f - tt) + Wrow[i1] * tt;
  }
  dst[i] = f2bf(v);
}

// xs = [x|m|t] -> bf16, zero-pad to Kpad. rows = 8192 (16 layers * 512 tok)
__global__ void prep_xs(const float* __restrict__ x, const float* __restrict__ m,
                        const float* __restrict__ t, ushort_t* __restrict__ dst,
                        int p, int Kpad) {
  int i = blockIdx.x * 256 + threadIdx.x;
  int total = 8192 * Kpad;
  if (i >= total) return;
  int r = i / Kpad, j = i - r * Kpad;
  float v = 0.f;
  int p3 = 3 * p;
  if (j < p3) {
    size_t base = (size_t)r * p;
    if (j < p)           v = x[base + j];
    else if (j < 2 * p)  v = m[base + j - p];
    else                 v = t[base + j - 2 * p];
  }
  dst[i] = f2bf(v);
}

// ---- 128x128 bf16 MFMA GEMM (m97-style: global_load_lds width-16) ------
// A: [M][Kpad] bf16 row-major; B: [N][Kpad] bf16 row-major (i.e. B^T);
// C[m][n] = sum_k A[m][k]*B[n][k]
// MODE 0: phase-1. cols<INTER -> hidden = bf16(silu(acc+bias)); cols>=INTER
//         -> d_out = acc+bias (f32). Rows scattered by idxg (layer perm).
// MODE 1: phase-2. d_out += acc + bias.
template <int MODE>
__global__ __launch_bounds__(256)
void gemm128(const ushort_t* __restrict__ A, const ushort_t* __restrict__ B,
             int Kpad, const float* __restrict__ bias,
             ushort_t* __restrict__ hidden, float* __restrict__ outp,
             const int* __restrict__ idxg) {
  __shared__ __align__(16) ushort_t lA[128 * 32];
  __shared__ __align__(16) ushort_t lB[128 * 32];
  const int t = threadIdx.x;
  const int wave = t >> 6, lane = t & 63;
  const int tm = blockIdx.x * 128, tn = blockIdx.y * 128;

  // staging: 8 chunks of 1024B per tile; wave w handles chunks 2w, 2w+1
  const int chunk = wave * 2;
  const int srow = chunk * 16 + (lane >> 2);
  const int scol = (lane & 3) * 8;
  const ushort_t* gA0 = A + (size_t)(tm + srow) * Kpad + scol;
  const ushort_t* gA1 = gA0 + (size_t)16 * Kpad;
  const ushort_t* gB0 = B + (size_t)(tn + srow) * Kpad + scol;
  const ushort_t* gB1 = gB0 + (size_t)16 * Kpad;
  ushort_t* lA0 = lA + chunk * 512;
  ushort_t* lA1 = lA0 + 512;
  ushort_t* lB0 = lB + chunk * 512;
  ushort_t* lB1 = lB0 + 512;

  const int wr = wave >> 1, wc = wave & 1;
  const f32x4 zero = {0.f, 0.f, 0.f, 0.f};
  f32x4 acc[4][4];
#pragma unroll
  for (int m2 = 0; m2 < 4; ++m2)
#pragma unroll
    for (int n2 = 0; n2 < 4; ++n2) acc[m2][n2] = zero;

  const ushort_t* pa = lA + (wr * 64 + (lane & 15)) * 32 + (lane >> 4) * 8;
  const ushort_t* pb = lB + (wc * 64 + (lane & 15)) * 32 + (lane >> 4) * 8;

  for (int kk = 0; kk < Kpad; kk += 32) {
    gld_lds16(gA0, lA0); gld_lds16(gA1, lA1);
    gld_lds16(gB0, lB0); gld_lds16(gB1, lB1);
    gA0 += 32; gA1 += 32; gB0 += 32; gB1 += 32;
    __syncthreads();
    short8 aF[4], bF[4];
#pragma unroll
    for (int m2 = 0; m2 < 4; ++m2) aF[m2] = *(const short8*)(pa + m2 * 16 * 32);
#pragma unroll
    for (int n2 = 0; n2 < 4; ++n2) bF[n2] = *(const short8*)(pb + n2 * 16 * 32);
#pragma unroll
    for (int m2 = 0; m2 < 4; ++m2)
#pragma unroll
      for (int n2 = 0; n2 < 4; ++n2)
        acc[m2][n2] = __builtin_amdgcn_mfma_f32_16x16x32_bf16(
            aF[m2], bF[n2], acc[m2][n2], 0, 0, 0);
    __syncthreads();
  }

  int rowBase;
  if (MODE == 0) {
    const int layer = idxg[tm >> 9];          // 128-row tile stays in one layer
    rowBase = layer * N_TOK + (tm & (N_TOK - 1));
  } else {
    rowBase = tm;
  }

#pragma unroll
  for (int m2 = 0; m2 < 4; ++m2) {
#pragma unroll
    for (int n2 = 0; n2 < 4; ++n2) {
      const int colg = tn + wc * 64 + n2 * 16 + (lane & 15);
      const float bv = bias[colg];
#pragma unroll
      for (int r = 0; r < 4; ++r) {
        const int rowl = wr * 64 + m2 * 16 + (lane >> 4) * 4 + r;
        const float v = acc[m2][n2][r];
        if (MODE == 0) {
          const int grow = rowBase + rowl;
          if (colg < INTER) {
            float h = v + bv;
            h = h / (1.f + expf(-h));
            hidden[(size_t)grow * INTER + colg] = f2bf(h);
          } else {
            outp[(size_t)grow * EMBED + (colg - INTER)] = v + bv;
          }
        } else {
          float* po = outp + (size_t)(tm + rowl) * EMBED + colg;
          *po += v + bv;
        }
      }
    }
  }
}

// ---- launch -------------------------------------------------------------

extern "C" void kernel_launch(void* const* d_in, const int* in_sizes, int n_in,
                              void* d_out, int out_size, void* d_ws, size_t ws_size,
                              hipStream_t stream) {
  const float* xg[3] = {(const float*)d_in[0], (const float*)d_in[3], (const float*)d_in[6]};
  const float* mg[3] = {(const float*)d_in[1], (const float*)d_in[4], (const float*)d_in[7]};
  const float* tg[3] = {(const float*)d_in[2], (const float*)d_in[5], (const float*)d_in[8]};
  const int* idxg[3] = {(const int*)d_in[9], (const int*)d_in[10], (const int*)d_in[11]};
  const float* W_lin = (const float*)d_in[12];
  const float* b_lin = (const float*)d_in[13];
  const float* W_res = (const float*)d_in[14];
  const float* b_res = (const float*)d_in[15];
  const float* W_out = (const float*)d_in[16];
  const float* b_out = (const float*)d_in[17];
  float* out = (float*)d_out;

  char* ws = (char*)d_ws;
  size_t off = 0;
  auto alloc = [&](size_t b) -> char* {
    size_t o = (off + 255) & ~(size_t)255;
    off = o + b;
    return ws + o;
  };

  ushort_t* hidden = (ushort_t*)alloc((size_t)MROWS * INTER * 2);   // 201 MB
  const int Ps[3] = {16, 32, 64};
  const int Kp[3] = {64, 96, 192};
  ushort_t* xsw[3];
  ushort_t* wcat[3];
  for (int g = 0; g < 3; ++g) xsw[g]  = (ushort_t*)alloc((size_t)8192 * Kp[g] * 2);
  for (int g = 0; g < 3; ++g) wcat[g] = (ushort_t*)alloc((size_t)NCAT * Kp[g] * 2);
  ushort_t* wout = (ushort_t*)alloc((size_t)EMBED * INTER * 2);     // 8 MB
  float* bcat = (float*)alloc((size_t)NCAT * 4);

  prep_bcat<<<(NCAT + 255) / 256, 256, 0, stream>>>(b_lin, b_res, bcat);
  prep_wout<<<(EMBED * INTER) / 256, 256, 0, stream>>>(W_out, wout);
  for (int g = 0; g < 3; ++g) {
    int tw = NCAT * Kp[g];
    prep_wcat<<<(tw + 255) / 256, 256, 0, stream>>>(W_lin, W_res, wcat[g], 3 * Ps[g], Kp[g]);
    int tx = 8192 * Kp[g];
    prep_xs<<<(tx + 255) / 256, 256, 0, stream>>>(xg[g], mg[g], tg[g], xsw[g], Ps[g], Kp[g]);
  }
  // phase 1: per group, [8192 x Kp] @ [5120 x Kp]^T
  for (int g = 0; g < 3; ++g)
    gemm128<0><<<dim3(64, 40), 256, 0, stream>>>(xsw[g], wcat[g], Kp[g], bcat,
                                                 hidden, out, idxg[g]);
  // phase 2: [24576 x 4096] @ [1024 x 4096]^T, += into out
  gemm128<1><<<dim3(192, 8), 256, 0, stream>>>(hidden, wout, INTER, b_out,
                                               nullptr, out, nullptr);
}